// Round 7
// baseline (398.976 us; speedup 1.0000x reference)
//
#include <hip/hip_runtime.h>
#include <math.h>

#define NROW 8192
#define DDIM 128
#define CAP 16384
#define NITERS 100
#define NWARM 6
#define AC (1.0f / 8192.0f)

struct Entry { int i, j; float s, t; };

// ws layout (bytes):
// 0       : x2  float[NROW]              (32768)
// 32768   : y2  float[NROW]              (32768)
// 65536   : counts int[8]                { [0..2]=list counts (pre-seeded 8192 diag), [3..5]=off-diag active }
// 65568   : minx uint[64]                per-128-row-tile min of x2 (uint-ordered floats)
// 65824   : miny uint[64]
// 66080   : accum double[3][264]         { [0..4]=Su,Sv,Sux2,Svy2,Ssp [5]=R [6]=bu_f [7]=bv_f [8..]=P,Q }
// 72416   : lists Entry[3][CAP]          (786432) -> ends 858848
// 858848  : Xbf ushort[NROW*DDIM]        (2 MiB)  [OVERLAY after scan2_k: sdiag@858848 tdiag@957152 u_g@1055456 v_g@1153760]
// 2956000 : Ybf ushort[NROW*DDIM]        (2 MiB)  -> total 5053152

typedef __attribute__((ext_vector_type(8))) short frag_ab;   // 8 bf16
typedef __attribute__((ext_vector_type(4))) float frag_cd;   // 4 fp32

__device__ inline unsigned short f2bf(float f) {
    unsigned u = __float_as_uint(f);
    return (unsigned short)((u + 0x7FFFu + ((u >> 16) & 1u)) >> 16);  // RN-even
}

__global__ void init_k(int* counts, unsigned* minx, unsigned* miny,
                       double* accum, Entry* lists) {
    int idx = blockIdx.x * 256 + threadIdx.x;
    if (idx < 3) counts[idx] = NROW;
    else if (idx < 8) counts[idx] = 0;
    if (idx < 64) { minx[idx] = 0x7F800000u; miny[idx] = 0x7F800000u; }
    if (idx < 3 * 264) accum[idx] = 0.0;
    if (idx < 3 * NROW) {
        int p = idx >> 13, i = idx & (NROW - 1);
        Entry e; e.i = i; e.j = i; e.s = 0.f; e.t = 0.f;
        lists[(size_t)p * CAP + i] = e;
    }
}

// norms + fp32->bf16 conversion + per-tile norm minima
__global__ void norms_k(const float* __restrict__ X, const float* __restrict__ Y,
                        float* __restrict__ x2, float* __restrict__ y2,
                        unsigned* __restrict__ minx, unsigned* __restrict__ miny,
                        unsigned short* __restrict__ Xbf, unsigned short* __restrict__ Ybf) {
    int gw = (blockIdx.x * blockDim.x + threadIdx.x) >> 6;
    int lane = threadIdx.x & 63;
    if (gw >= 2 * NROW) return;
    const float* M = (gw < NROW) ? X : Y;
    float* out = (gw < NROW) ? x2 : y2;
    unsigned* mn = (gw < NROW) ? minx : miny;
    unsigned short* Mb = (gw < NROW) ? Xbf : Ybf;
    int r = (gw < NROW) ? gw : gw - NROW;
    float2 v = *(const float2*)(M + (size_t)r * DDIM + lane * 2);
    unsigned pk = (unsigned)f2bf(v.x) | ((unsigned)f2bf(v.y) << 16);
    *(unsigned*)(Mb + (size_t)r * DDIM + lane * 2) = pk;
    float s = v.x * v.x + v.y * v.y;
    for (int o = 32; o; o >>= 1) s += __shfl_down(s, o, 64);
    if (lane == 0) {
        out[r] = s;
        atomicMin(&mn[r >> 7], __float_as_uint(s));   // s>=0: uint order == float order
    }
}

// Persistent row-block MFMA scan: A-frags in registers, B streamed through
// double-buffered XOR-swizzled LDS (conflict-free), per-tile norm-min fast reject.
__global__ __launch_bounds__(256) void scan2_k(const unsigned short* __restrict__ Xbf,
                                               const unsigned short* __restrict__ Ybf,
                                               const float* __restrict__ x2,
                                               const float* __restrict__ y2,
                                               const unsigned* __restrict__ minx,
                                               const unsigned* __restrict__ miny,
                                               int* counts, Entry* lists) {
    int p = blockIdx.y;
    int bx = blockIdx.x;
    const unsigned short* Ab = (p == 2) ? Ybf : Xbf;
    const unsigned short* Bb = (p == 0) ? Ybf : ((p == 1) ? Xbf : Ybf);
    const float* na = (p == 2) ? y2 : x2;
    const float* nb = (p == 0) ? y2 : ((p == 1) ? x2 : y2);
    const unsigned* mAarr = (p == 2) ? miny : minx;
    const unsigned* mBarr = (p == 0) ? miny : ((p == 1) ? minx : miny);
    int i0 = bx * 128;
    int jt0 = (p == 0) ? 0 : bx;   // symmetric pairs: upper triangle incl diagonal

    __shared__ uint4 Bs[2][2048];  // 2 x 32KB, unit u of row r stored at u^(r&7)
    int t = threadIdx.x;
    int w = t >> 6, lane = t & 63, lm = lane & 15, quad = lane >> 4;
    int wr = (w & 1) * 64, wc = (w >> 1) * 64;

    // A-fragments direct from global (L2-resident), once per block
    frag_ab a[4][4];
    #pragma unroll
    for (int rt = 0; rt < 4; rt++)
        #pragma unroll
        for (int ks = 0; ks < 4; ks++)
            a[rt][ks] = *(const frag_ab*)(Ab + (size_t)(i0 + wr + rt * 16 + lm) * DDIM + quad * 8 + ks * 32);

    float mA = __uint_as_float(mAarr[bx]);
    Entry* list = lists + (size_t)p * CAP;

    // prefetch + stage first B tile
    uint4 st[8];
    {
        const uint4* gB = (const uint4*)(Bb + (size_t)jt0 * 128 * DDIM);
        #pragma unroll
        for (int c = 0; c < 8; c++) st[c] = gB[c * 256 + t];
        #pragma unroll
        for (int c = 0; c < 8; c++) {
            int g = c * 256 + t, row = g >> 4, u = g & 15;
            Bs[0][row * 16 + (u ^ (row & 7))] = st[c];
        }
    }
    __syncthreads();

    int par = 0;
    for (int jt = jt0; jt < 64; jt++) {
        // issue prefetch of next tile (consumed after compute)
        if (jt + 1 < 64) {
            const uint4* gN = (const uint4*)(Bb + (size_t)(jt + 1) * 128 * DDIM);
            #pragma unroll
            for (int c = 0; c < 8; c++) st[c] = gN[c * 256 + t];
        }
        // compute 64x64 per wave via 16 MFMA tiles
        frag_cd acc[4][4];
        #pragma unroll
        for (int rt = 0; rt < 4; rt++)
            #pragma unroll
            for (int ct = 0; ct < 4; ct++) acc[rt][ct] = (frag_cd){0.f, 0.f, 0.f, 0.f};
        #pragma unroll
        for (int ks = 0; ks < 4; ks++) {
            frag_ab b[4];
            #pragma unroll
            for (int ct = 0; ct < 4; ct++) {
                int row = wc + ct * 16 + lm;
                b[ct] = *(const frag_ab*)&Bs[par][row * 16 + ((quad + 4 * ks) ^ (row & 7))];
            }
            #pragma unroll
            for (int rt = 0; rt < 4; rt++)
                #pragma unroll
                for (int ct = 0; ct < 4; ct++)
                    acc[rt][ct] = __builtin_amdgcn_mfma_f32_16x16x32_bf16(a[rt][ks], b[ct], acc[rt][ct], 0, 0, 0);
        }
        // epilogue: conservative per-tile reject, exact check only on hits
        float mB = __uint_as_float(mBarr[jt]);
        float thr = 0.5f * (mA + mB - 2.0f);
        int j0 = jt * 128;
        #pragma unroll
        for (int rt = 0; rt < 4; rt++) {
            #pragma unroll
            for (int ct = 0; ct < 4; ct++) {
                frag_cd A4 = acc[rt][ct];
                float m4 = fmaxf(fmaxf(A4[0], A4[1]), fmaxf(A4[2], A4[3]));
                if (__any(m4 > thr)) {
                    int j = j0 + wc + ct * 16 + lm;
                    float yj = nb[j];
                    #pragma unroll
                    for (int reg = 0; reg < 4; reg++) {
                        int i = i0 + wr + rt * 16 + quad * 4 + reg;
                        float Ct = na[i] + yj - 2.f * A4[reg];
                        if (Ct < 2.0f && i != j) {
                            if (p == 0) {
                                int idx = atomicAdd(&counts[0], 1);
                                if (idx < CAP) { Entry e; e.i = i; e.j = j; e.s = 0.f; e.t = 0.f; list[idx] = e; }
                            } else if (i < j) {
                                int idx = atomicAdd(&counts[p], 2);
                                if (idx < CAP) { Entry e; e.i = i; e.j = j; e.s = 0.f; e.t = 0.f; list[idx] = e; }
                                if (idx + 1 < CAP) { Entry e; e.i = j; e.j = i; e.s = 0.f; e.t = 0.f; list[idx + 1] = e; }
                            }
                        }
                    }
                }
            }
        }
        // stage next tile into the other buffer; one barrier per iteration
        if (jt + 1 < 64) {
            #pragma unroll
            for (int c = 0; c < 8; c++) {
                int g = c * 256 + t, row = g >> 4, u = g & 15;
                Bs[par ^ 1][row * 16 + (u ^ (row & 7))] = st[c];
            }
        }
        __syncthreads();
        par ^= 1;
    }
}

// exact: full 128-dim fp32 distance for every listed entry.
__global__ __launch_bounds__(256) void exact_k(const float* __restrict__ X,
                                               const float* __restrict__ Y,
                                               const float* __restrict__ x2,
                                               const float* __restrict__ y2,
                                               const int* counts, Entry* lists) {
    int p = blockIdx.y;
    const float* A = (p == 2) ? Y : X;
    const float* B = (p == 0) ? Y : ((p == 1) ? X : Y);
    const float* na = (p == 2) ? y2 : x2;
    const float* nb = (p == 0) ? y2 : ((p == 1) ? x2 : y2);
    int cnt = counts[p]; if (cnt > CAP) cnt = CAP;
    Entry* list = lists + (size_t)p * CAP;
    int w = (blockIdx.x * 256 + threadIdx.x) >> 6;
    int lane = threadIdx.x & 63;
    for (int e = w; e < cnt; e += 8192) {
        int i = list[e].i, j = list[e].j;
        const float* ar = A + (size_t)i * DDIM;
        const float* br = B + (size_t)j * DDIM;
        float dot = ar[lane] * br[lane] + ar[lane + 64] * br[lane + 64];
        for (int o = 32; o; o >>= 1) dot += __shfl_down(dot, o, 64);
        if (lane == 0) {
            float raw = na[i] + nb[j] - 2.0f * dot;
            float C = fmaxf(raw, 0.0f);
            float sc = fmaxf(-C * 100.0f, -50.0f);
            float K = fmaxf(expf(sc), 1e-8f);
            float s = K - 1e-8f;
            list[e].s = s;
            list[e].t = (raw >= 0.f) ? s * C : (-1e-8f) * raw;   // exactly 0 when s==0
        }
    }
}

// compact: diagonal entries -> dense arrays; count active off-diagonal entries
__global__ void compact_k(const int* counts, const Entry* __restrict__ lists,
                          float* __restrict__ sdiag, float* __restrict__ tdiag,
                          int* rescnt) {
    int p = blockIdx.y;
    int cnt = counts[p]; if (cnt > CAP) cnt = CAP;
    int e = blockIdx.x * 256 + threadIdx.x;
    if (e >= cnt) return;
    Entry en = lists[(size_t)p * CAP + e];
    if (en.i == en.j) {
        sdiag[p * NROW + en.i] = en.s;
        tdiag[p * NROW + en.i] = en.t;
    } else if (en.s != 0.f || en.t != 0.f) {
        atomicAdd(&rescnt[p], 1);
    }
}

// Warm Sinkhorn: NWARM exact coupled iterations, then freeze bases -> sinkwide_k.
__global__ __launch_bounds__(1024, 1) void sink2_k(const int* counts,
                                                   const Entry* __restrict__ lists,
                                                   const float* __restrict__ sdiag,
                                                   float* __restrict__ u_g,
                                                   float* __restrict__ v_g,
                                                   double* accum) {
    int p = blockIdx.x;
    const Entry* list = lists + (size_t)p * CAP;
    int cnt = counts[p]; if (cnt > CAP) cnt = CAP;
    int nres = counts[3 + p];
    double* acc = accum + (size_t)p * 264;
    float* up = u_g + (size_t)p * NROW;
    float* vp = v_g + (size_t)p * NROW;

    __shared__ float u_s[NROW];   // fallback only
    __shared__ float v_s[NROW];
    __shared__ float redS[2][16];
    __shared__ unsigned redC[16];
    int t = threadIdx.x;
    int wid = t >> 6, lane = t & 63;

    if (nres == 0) {
        float vk[8], uk[8], sk[8];
        unsigned pv2[8];
        #pragma unroll
        for (int k = 0; k < 8; k++) {
            sk[k] = sdiag[p * NROW + t + 1024 * k];
            vk[k] = 1.0f; uk[k] = AC; pv2[k] = 0xFFFFFFFFu;
        }
        unsigned flags = 3u;
        int par = 0, last = 0, done = 0;
        float bu_last = 0.f;
        for (int it = 0; it < NWARM; it++) {
            float s = 0.f;
            #pragma unroll
            for (int k = 0; k < 8; k++) s += vk[k];
            for (int o = 32; o; o >>= 1) s += __shfl_down(s, o, 64);
            if (lane == 0) { redS[par][wid] = s; redC[wid] = flags; }
            __syncthreads();
            float sumv = 0.f; unsigned anyf = 0;
            #pragma unroll
            for (int w2 = 0; w2 < 16; w2++) { sumv += redS[par][w2]; anyf |= redC[w2]; }
            par ^= 1;
            if (it > 0) {
                if (!(anyf & 1)) { done = 1; break; }
                if (!(anyf & 2)) {
                    if (((NITERS - it) & 1) == 0) { done = 1; break; }
                    last = 1;
                }
            }
            float base = 1e-8f * sumv;
            #pragma unroll
            for (int k = 0; k < 8; k++) {
                float kv = fmaxf(base + sk[k] * vk[k], 1e-8f);
                uk[k] = AC * __builtin_amdgcn_rcpf(kv);
            }
            s = 0.f;
            #pragma unroll
            for (int k = 0; k < 8; k++) s += uk[k];
            for (int o = 32; o; o >>= 1) s += __shfl_down(s, o, 64);
            if (lane == 0) redS[par][wid] = s;
            __syncthreads();
            float sumu = 0.f;
            #pragma unroll
            for (int w2 = 0; w2 < 16; w2++) sumu += redS[par][w2];
            par ^= 1;
            base = 1e-8f * sumu;
            bu_last = base;
            unsigned d1 = 0, d2 = 0;
            #pragma unroll
            for (int k = 0; k < 8; k++) {
                float kv = fmaxf(base + sk[k] * uk[k], 1e-8f);
                float nv = AC * __builtin_amdgcn_rcpf(kv);
                unsigned nb_ = __float_as_uint(nv);
                d1 |= nb_ ^ __float_as_uint(vk[k]);
                d2 |= nb_ ^ pv2[k];
                pv2[k] = __float_as_uint(vk[k]);
                vk[k] = nv;
            }
            flags = (__any(d1 != 0) ? 1u : 0u) | (__any(d2 != 0) ? 2u : 0u);
            if (last) { done = 1; break; }
        }
        float bv_f = 0.f;
        int R = 0;
        if (!done) {
            float s = 0.f;
            #pragma unroll
            for (int k = 0; k < 8; k++) s += vk[k];
            for (int o = 32; o; o >>= 1) s += __shfl_down(s, o, 64);
            if (lane == 0) redS[par][wid] = s;
            __syncthreads();
            float sumv = 0.f;
            #pragma unroll
            for (int w2 = 0; w2 < 16; w2++) sumv += redS[par][w2];
            bv_f = 1e-8f * sumv;
            R = NITERS - NWARM;
        }
        #pragma unroll
        for (int k = 0; k < 8; k++) {
            int i = t + 1024 * k;
            up[i] = uk[k]; vp[i] = vk[k];
        }
        if (t == 0) { acc[5] = (double)R; acc[6] = (double)bu_last; acc[7] = (double)bv_f; }
    } else {
        // fallback: general sparse scatter, full 100 iterations
        for (int i = t; i < NROW; i += 1024) { u_s[i] = 1.0f; v_s[i] = 1.0f; }
        __syncthreads();
        for (int it = 0; it < NITERS; it++) {
            {
                float sv = 0.f;
                for (int i = t; i < NROW; i += 1024) sv += v_s[i];
                for (int o = 32; o; o >>= 1) sv += __shfl_down(sv, o, 64);
                if (lane == 0) u_s[wid] = sv;
                __syncthreads();
                if (t < 64) {
                    float s2 = (t < 16) ? u_s[t] : 0.f;
                    for (int o = 8; o; o >>= 1) s2 += __shfl_down(s2, o, 64);
                    if (t == 0) u_s[0] = s2;
                }
                __syncthreads();
                float sum_v = u_s[0];
                __syncthreads();
                for (int i = t; i < NROW; i += 1024) u_s[i] = 1e-8f * sum_v;
                __syncthreads();
                for (int e = t; e < cnt; e += 1024)
                    atomicAdd(&u_s[list[e].i], list[e].s * v_s[list[e].j]);
                __syncthreads();
                for (int i = t; i < NROW; i += 1024) u_s[i] = AC / fmaxf(u_s[i], 1e-8f);
                __syncthreads();
            }
            {
                float su = 0.f;
                for (int i = t; i < NROW; i += 1024) su += u_s[i];
                for (int o = 32; o; o >>= 1) su += __shfl_down(su, o, 64);
                if (lane == 0) v_s[wid] = su;
                __syncthreads();
                if (t < 64) {
                    float s2 = (t < 16) ? v_s[t] : 0.f;
                    for (int o = 8; o; o >>= 1) s2 += __shfl_down(s2, o, 64);
                    if (t == 0) v_s[0] = s2;
                }
                __syncthreads();
                float sum_u = v_s[0];
                __syncthreads();
                for (int i = t; i < NROW; i += 1024) v_s[i] = 1e-8f * sum_u;
                __syncthreads();
                for (int e = t; e < cnt; e += 1024)
                    atomicAdd(&v_s[list[e].j], list[e].s * u_s[list[e].i]);
                __syncthreads();
                for (int i = t; i < NROW; i += 1024) v_s[i] = AC / fmaxf(v_s[i], 1e-8f);
                __syncthreads();
            }
        }
        for (int i = t; i < NROW; i += 1024) { up[i] = u_s[i]; vp[i] = v_s[i]; }
        if (t == 0) { acc[5] = 0.0; acc[6] = 0.0; acc[7] = 0.0; }
    }
}

// Frozen-base per-lane iterations: no barriers, no cross-lane traffic.
__global__ __launch_bounds__(256) void sinkwide_k(const float* __restrict__ sdiag,
                                                  float* __restrict__ u_g,
                                                  float* __restrict__ v_g,
                                                  const double* __restrict__ accum) {
    int p = blockIdx.y;
    const double* acc = accum + (size_t)p * 264;
    int R = (int)acc[5];
    if (R <= 0) return;
    float bu = (float)acc[6], bv = (float)acc[7];
    int i = blockIdx.x * 256 + threadIdx.x;
    float s = sdiag[p * NROW + i];
    float v = v_g[p * NROW + i];
    float u = u_g[p * NROW + i];
    for (int r = 0; r < R; r++) {
        u = AC * __builtin_amdgcn_rcpf(fmaxf(bv + s * v, 1e-8f));
        v = AC * __builtin_amdgcn_rcpf(fmaxf(bu + s * u, 1e-8f));
    }
    u_g[p * NROW + i] = u;
    v_g[p * NROW + i] = v;
}

// off-diagonal sparse cost correction (diagonal handled in epi_k via tdiag)
__global__ void sp_k(const int* counts, const Entry* __restrict__ lists,
                     const float* __restrict__ u_g, const float* __restrict__ v_g,
                     double* accum) {
    int p = blockIdx.x;
    int cnt = counts[p]; if (cnt > CAP) cnt = CAP;
    const Entry* list = lists + (size_t)p * CAP;
    const float* up = u_g + (size_t)p * NROW;
    const float* vp = v_g + (size_t)p * NROW;
    __shared__ double red[4];
    int t = threadIdx.x, lane = t & 63, wid = t >> 6;
    double sp = 0.0;
    for (int e = t; e < cnt; e += 256) {
        Entry en = list[e];
        if (en.i != en.j && en.t != 0.f)
            sp += (double)up[en.i] * (double)vp[en.j] * (double)en.t;
    }
    for (int o = 32; o; o >>= 1) sp += __shfl_down(sp, o, 64);
    if (lane == 0) red[wid] = sp;
    __syncthreads();
    if (t == 0) {
        double tot = red[0] + red[1] + red[2] + red[3];
        atomicAdd(&accum[(size_t)p * 264 + 4], tot);
    }
}

// wide-grid epilogue: Su, Sv, Sux2, Svy2, diag-sp, P[d], Q[d]
__global__ __launch_bounds__(256) void epi_k(const float* __restrict__ X,
                                             const float* __restrict__ Y,
                                             const float* __restrict__ x2,
                                             const float* __restrict__ y2,
                                             const float* __restrict__ u_g,
                                             const float* __restrict__ v_g,
                                             const float* __restrict__ tdiag,
                                             double* accum) {
    int p = blockIdx.y;
    const float* A = (p == 2) ? Y : X;
    const float* B = (p == 0) ? Y : ((p == 1) ? X : Y);
    const float* na = (p == 2) ? y2 : x2;
    const float* nb = (p == 0) ? y2 : ((p == 1) ? x2 : y2);
    const float* up = u_g + (size_t)p * NROW;
    const float* vp = v_g + (size_t)p * NROW;
    double* acc = accum + (size_t)p * 264;
    int t = threadIdx.x, lane = t & 63;
    int rbase = blockIdx.x * 256;
    {
        int r = rbase + t;
        double ui = up[r], vi = vp[r];
        double a0 = ui, a1 = vi, a2 = ui * (double)na[r], a3 = vi * (double)nb[r];
        double a4 = ui * vi * (double)tdiag[p * NROW + r];
        for (int o = 32; o; o >>= 1) {
            a0 += __shfl_down(a0, o, 64); a1 += __shfl_down(a1, o, 64);
            a2 += __shfl_down(a2, o, 64); a3 += __shfl_down(a3, o, 64);
            a4 += __shfl_down(a4, o, 64);
        }
        if (lane == 0) {
            atomicAdd(&acc[0], a0); atomicAdd(&acc[1], a1);
            atomicAdd(&acc[2], a2); atomicAdd(&acc[3], a3);
            atomicAdd(&acc[4], a4);
        }
    }
    {
        int dq = (t & 31) * 4, g = t >> 5;
        double pp[4] = {0, 0, 0, 0}, qq[4] = {0, 0, 0, 0};
        for (int k = 0; k < 32; k++) {
            int r = rbase + g + 8 * k;
            float4 av = *(const float4*)(A + (size_t)r * DDIM + dq);
            float us = up[r];
            pp[0] += (double)us * av.x; pp[1] += (double)us * av.y;
            pp[2] += (double)us * av.z; pp[3] += (double)us * av.w;
            float4 bv = *(const float4*)(B + (size_t)r * DDIM + dq);
            float vs = vp[r];
            qq[0] += (double)vs * bv.x; qq[1] += (double)vs * bv.y;
            qq[2] += (double)vs * bv.z; qq[3] += (double)vs * bv.w;
        }
        #pragma unroll
        for (int m = 0; m < 4; m++) {
            atomicAdd(&acc[8 + dq + m], pp[m]);
            atomicAdd(&acc[136 + dq + m], qq[m]);
        }
    }
}

__global__ void combine_k(const double* __restrict__ accum, float* __restrict__ out) {
    int t = threadIdx.x;  // 64 threads
    __shared__ double costs[3];
    for (int p = 0; p < 3; p++) {
        const double* acc = accum + (size_t)p * 264;
        double part = acc[8 + t] * acc[136 + t] + acc[8 + 64 + t] * acc[136 + 64 + t];
        for (int o = 32; o; o >>= 1) part += __shfl_down(part, o, 64);
        if (t == 0) {
            double F = acc[2] * acc[1] + acc[0] * acc[3] - 2.0 * part;
            double c = 1e-8 * F + acc[4];
            costs[p] = (c > 0.0) ? c : 0.0;
        }
    }
    __syncthreads();
    if (t == 0) {
        double dv = costs[0] - 0.5 * (costs[1] + costs[2]);
        dv = fmin(fmax(dv, 0.0), 10000.0);
        out[0] = (float)dv;
    }
}

extern "C" void kernel_launch(void* const* d_in, const int* in_sizes, int n_in,
                              void* d_out, int out_size, void* d_ws, size_t ws_size,
                              hipStream_t stream) {
    const float* X = (const float*)d_in[0];
    const float* Y = (const float*)d_in[1];
    float* out = (float*)d_out;
    char* ws = (char*)d_ws;
    float* x2 = (float*)ws;
    float* y2 = (float*)(ws + 32768);
    int* counts = (int*)(ws + 65536);
    unsigned* minx = (unsigned*)(ws + 65568);
    unsigned* miny = (unsigned*)(ws + 65824);
    double* accum = (double*)(ws + 66080);
    Entry* lists = (Entry*)(ws + 72416);
    unsigned short* Xbf = (unsigned short*)(ws + 858848);    // overlay region
    float* sdiag = (float*)(ws + 858848);
    float* tdiag = (float*)(ws + 957152);
    float* u_g = (float*)(ws + 1055456);
    float* v_g = (float*)(ws + 1153760);
    unsigned short* Ybf = (unsigned short*)(ws + 2956000);

    init_k<<<(3 * NROW + 255) / 256, 256, 0, stream>>>(counts, minx, miny, accum, lists);
    norms_k<<<(2 * NROW) / 4, 256, 0, stream>>>(X, Y, x2, y2, minx, miny, Xbf, Ybf);
    scan2_k<<<dim3(64, 3), 256, 0, stream>>>(Xbf, Ybf, x2, y2, minx, miny, counts, lists);
    exact_k<<<dim3(2048, 3), 256, 0, stream>>>(X, Y, x2, y2, counts, lists);
    compact_k<<<dim3(CAP / 256, 3), 256, 0, stream>>>(counts, lists, sdiag, tdiag, counts + 3);
    sink2_k<<<3, 1024, 0, stream>>>(counts, lists, sdiag, u_g, v_g, accum);
    sinkwide_k<<<dim3(NROW / 256, 3), 256, 0, stream>>>(sdiag, u_g, v_g, accum);
    sp_k<<<3, 256, 0, stream>>>(counts, lists, u_g, v_g, accum);
    epi_k<<<dim3(NROW / 256, 3), 256, 0, stream>>>(X, Y, x2, y2, u_g, v_g, tdiag, accum);
    combine_k<<<1, 64, 0, stream>>>(accum, out);
}

// Round 8
// 258.154 us; speedup vs baseline: 1.5455x; 1.5455x over previous
//
#include <hip/hip_runtime.h>
#include <math.h>

#define NROW 8192
#define DDIM 128
#define CAP 16384
#define NITERS 100
#define NWARM 6
#define AC (1.0f / 8192.0f)

struct Entry { int i, j; float s, t; };

// ws layout (bytes):
// 0       : x2  float[NROW]              (32768)
// 32768   : y2  float[NROW]              (32768)
// 65536   : counts int[8]                { [0..2]=list counts (pre-seeded 8192 diag), [3..5]=off-diag active }
// 65568   : minx uint[64]                per-128-row-tile min of x2 (uint-ordered floats)
// 65824   : miny uint[64]
// 66080   : accum double[3][264]         { [0..4]=Su,Sv,Sux2,Svy2,Ssp [5]=R [6]=bu_f [7]=bv_f [8..]=P,Q }
// 72416   : lists Entry[3][CAP]          (786432) -> ends 858848
// 858848  : Xbf ushort[NROW*DDIM]        (2 MiB)  [OVERLAY after scan3_k: sdiag@858848 tdiag@957152 u_g@1055456 v_g@1153760]
// 2956000 : Ybf ushort[NROW*DDIM]        (2 MiB)  -> total 5053152

typedef __attribute__((ext_vector_type(8))) short frag_ab;   // 8 bf16
typedef __attribute__((ext_vector_type(4))) float frag_cd;   // 4 fp32

__device__ inline unsigned short f2bf(float f) {
    unsigned u = __float_as_uint(f);
    return (unsigned short)((u + 0x7FFFu + ((u >> 16) & 1u)) >> 16);  // RN-even
}

__global__ void init_k(int* counts, unsigned* minx, unsigned* miny,
                       double* accum, Entry* lists) {
    int idx = blockIdx.x * 256 + threadIdx.x;
    if (idx < 3) counts[idx] = NROW;
    else if (idx < 8) counts[idx] = 0;
    if (idx < 64) { minx[idx] = 0x7F800000u; miny[idx] = 0x7F800000u; }
    if (idx < 3 * 264) accum[idx] = 0.0;
    if (idx < 3 * NROW) {
        int p = idx >> 13, i = idx & (NROW - 1);
        Entry e; e.i = i; e.j = i; e.s = 0.f; e.t = 0.f;
        lists[(size_t)p * CAP + i] = e;
    }
}

// norms + fp32->bf16 conversion + per-tile norm minima
__global__ void norms_k(const float* __restrict__ X, const float* __restrict__ Y,
                        float* __restrict__ x2, float* __restrict__ y2,
                        unsigned* __restrict__ minx, unsigned* __restrict__ miny,
                        unsigned short* __restrict__ Xbf, unsigned short* __restrict__ Ybf) {
    int gw = (blockIdx.x * blockDim.x + threadIdx.x) >> 6;
    int lane = threadIdx.x & 63;
    if (gw >= 2 * NROW) return;
    const float* M = (gw < NROW) ? X : Y;
    float* out = (gw < NROW) ? x2 : y2;
    unsigned* mn = (gw < NROW) ? minx : miny;
    unsigned short* Mb = (gw < NROW) ? Xbf : Ybf;
    int r = (gw < NROW) ? gw : gw - NROW;
    float2 v = *(const float2*)(M + (size_t)r * DDIM + lane * 2);
    unsigned pk = (unsigned)f2bf(v.x) | ((unsigned)f2bf(v.y) << 16);
    *(unsigned*)(Mb + (size_t)r * DDIM + lane * 2) = pk;
    float s = v.x * v.x + v.y * v.y;
    for (int o = 32; o; o >>= 1) s += __shfl_down(s, o, 64);
    if (lane == 0) {
        out[r] = s;
        atomicMin(&mn[r >> 7], __float_as_uint(s));   // s>=0: uint order == float order
    }
}

// Tile-per-block MFMA scan with XOR-swizzled LDS (conflict-free frag reads)
// and norm-min fast-reject epilogue. 16B unit u of row r stored at u^(r&7).
__global__ __launch_bounds__(256) void scan3_k(const unsigned short* __restrict__ Xbf,
                                               const unsigned short* __restrict__ Ybf,
                                               const float* __restrict__ x2,
                                               const float* __restrict__ y2,
                                               const unsigned* __restrict__ minx,
                                               const unsigned* __restrict__ miny,
                                               int* counts, Entry* lists) {
    int p = blockIdx.z;
    if (p && blockIdx.y < blockIdx.x) return;   // symmetric pairs: upper triangle only
    const unsigned short* Ab = (p == 2) ? Ybf : Xbf;
    const unsigned short* Bb = (p == 0) ? Ybf : ((p == 1) ? Xbf : Ybf);
    const float* na = (p == 2) ? y2 : x2;
    const float* nb = (p == 0) ? y2 : ((p == 1) ? x2 : y2);
    const unsigned* mAarr = (p == 2) ? miny : minx;
    const unsigned* mBarr = (p == 0) ? miny : ((p == 1) ? minx : miny);
    int i0 = blockIdx.x * 128, j0 = blockIdx.y * 128;

    __shared__ uint4 As[2048];   // 32KB
    __shared__ uint4 Bs[2048];   // 32KB
    int t = threadIdx.x;
    {
        const uint4* ga = (const uint4*)(Ab + (size_t)i0 * DDIM);
        const uint4* gb = (const uint4*)(Bb + (size_t)j0 * DDIM);
        #pragma unroll
        for (int c = 0; c < 8; c++) {
            int g = c * 256 + t, row = g >> 4, u = g & 15;
            int d = row * 16 + (u ^ (row & 7));
            As[d] = ga[g];
            Bs[d] = gb[g];
        }
    }
    __syncthreads();

    int w = t >> 6, lane = t & 63, lm = lane & 15, quad = lane >> 4;
    int wr = (w & 1) * 64, wc = (w >> 1) * 64;

    frag_cd acc[4][4];
    #pragma unroll
    for (int rt = 0; rt < 4; rt++)
        #pragma unroll
        for (int ct = 0; ct < 4; ct++) acc[rt][ct] = (frag_cd){0.f, 0.f, 0.f, 0.f};

    #pragma unroll
    for (int ks = 0; ks < 4; ks++) {
        frag_ab a[4], b[4];
        #pragma unroll
        for (int rt = 0; rt < 4; rt++) {
            int row = wr + rt * 16 + lm;
            a[rt] = *(const frag_ab*)&As[row * 16 + ((quad + 4 * ks) ^ (row & 7))];
        }
        #pragma unroll
        for (int ct = 0; ct < 4; ct++) {
            int row = wc + ct * 16 + lm;
            b[ct] = *(const frag_ab*)&Bs[row * 16 + ((quad + 4 * ks) ^ (row & 7))];
        }
        #pragma unroll
        for (int rt = 0; rt < 4; rt++)
            #pragma unroll
            for (int ct = 0; ct < 4; ct++)
                acc[rt][ct] = __builtin_amdgcn_mfma_f32_16x16x32_bf16(a[rt], b[ct], acc[rt][ct], 0, 0, 0);
    }

    // fast-reject epilogue: tile survives only if some dot > thr (exact lower bound)
    float mA = __uint_as_float(mAarr[blockIdx.x]);
    float mB = __uint_as_float(mBarr[blockIdx.y]);
    float thr = 0.5f * (mA + mB - 2.0f);
    Entry* list = lists + (size_t)p * CAP;
    #pragma unroll
    for (int rt = 0; rt < 4; rt++) {
        #pragma unroll
        for (int ct = 0; ct < 4; ct++) {
            frag_cd A4 = acc[rt][ct];
            float m4 = fmaxf(fmaxf(A4[0], A4[1]), fmaxf(A4[2], A4[3]));
            if (__any(m4 > thr)) {
                int j = j0 + wc + ct * 16 + lm;
                float yj = nb[j];
                #pragma unroll
                for (int reg = 0; reg < 4; reg++) {
                    int i = i0 + wr + rt * 16 + quad * 4 + reg;
                    float Ct = na[i] + yj - 2.f * A4[reg];
                    if (Ct < 2.0f && i != j) {
                        if (p == 0) {
                            int idx = atomicAdd(&counts[0], 1);
                            if (idx < CAP) { Entry e; e.i = i; e.j = j; e.s = 0.f; e.t = 0.f; list[idx] = e; }
                        } else if (i < j) {
                            int idx = atomicAdd(&counts[p], 2);
                            if (idx < CAP) { Entry e; e.i = i; e.j = j; e.s = 0.f; e.t = 0.f; list[idx] = e; }
                            if (idx + 1 < CAP) { Entry e; e.i = j; e.j = i; e.s = 0.f; e.t = 0.f; list[idx + 1] = e; }
                        }
                    }
                }
            }
        }
    }
}

// exact: full 128-dim fp32 distance for every listed entry.
__global__ __launch_bounds__(256) void exact_k(const float* __restrict__ X,
                                               const float* __restrict__ Y,
                                               const float* __restrict__ x2,
                                               const float* __restrict__ y2,
                                               const int* counts, Entry* lists) {
    int p = blockIdx.y;
    const float* A = (p == 2) ? Y : X;
    const float* B = (p == 0) ? Y : ((p == 1) ? X : Y);
    const float* na = (p == 2) ? y2 : x2;
    const float* nb = (p == 0) ? y2 : ((p == 1) ? x2 : y2);
    int cnt = counts[p]; if (cnt > CAP) cnt = CAP;
    Entry* list = lists + (size_t)p * CAP;
    int w = (blockIdx.x * 256 + threadIdx.x) >> 6;
    int lane = threadIdx.x & 63;
    for (int e = w; e < cnt; e += 8192) {
        int i = list[e].i, j = list[e].j;
        const float* ar = A + (size_t)i * DDIM;
        const float* br = B + (size_t)j * DDIM;
        float dot = ar[lane] * br[lane] + ar[lane + 64] * br[lane + 64];
        for (int o = 32; o; o >>= 1) dot += __shfl_down(dot, o, 64);
        if (lane == 0) {
            float raw = na[i] + nb[j] - 2.0f * dot;
            float C = fmaxf(raw, 0.0f);
            float sc = fmaxf(-C * 100.0f, -50.0f);
            float K = fmaxf(expf(sc), 1e-8f);
            float s = K - 1e-8f;
            list[e].s = s;
            list[e].t = (raw >= 0.f) ? s * C : (-1e-8f) * raw;   // exactly 0 when s==0
        }
    }
}

// compact: diagonal entries -> dense arrays; count active off-diagonal entries
__global__ void compact_k(const int* counts, const Entry* __restrict__ lists,
                          float* __restrict__ sdiag, float* __restrict__ tdiag,
                          int* rescnt) {
    int p = blockIdx.y;
    int cnt = counts[p]; if (cnt > CAP) cnt = CAP;
    int e = blockIdx.x * 256 + threadIdx.x;
    if (e >= cnt) return;
    Entry en = lists[(size_t)p * CAP + e];
    if (en.i == en.j) {
        sdiag[p * NROW + en.i] = en.s;
        tdiag[p * NROW + en.i] = en.t;
    } else if (en.s != 0.f || en.t != 0.f) {
        atomicAdd(&rescnt[p], 1);
    }
}

// Warm Sinkhorn: NWARM exact coupled iterations, then freeze bases -> sinkwide_k.
__global__ __launch_bounds__(1024, 1) void sink2_k(const int* counts,
                                                   const Entry* __restrict__ lists,
                                                   const float* __restrict__ sdiag,
                                                   float* __restrict__ u_g,
                                                   float* __restrict__ v_g,
                                                   double* accum) {
    int p = blockIdx.x;
    const Entry* list = lists + (size_t)p * CAP;
    int cnt = counts[p]; if (cnt > CAP) cnt = CAP;
    int nres = counts[3 + p];
    double* acc = accum + (size_t)p * 264;
    float* up = u_g + (size_t)p * NROW;
    float* vp = v_g + (size_t)p * NROW;

    __shared__ float u_s[NROW];   // fallback only
    __shared__ float v_s[NROW];
    __shared__ float redS[2][16];
    __shared__ unsigned redC[16];
    int t = threadIdx.x;
    int wid = t >> 6, lane = t & 63;

    if (nres == 0) {
        float vk[8], uk[8], sk[8];
        unsigned pv2[8];
        #pragma unroll
        for (int k = 0; k < 8; k++) {
            sk[k] = sdiag[p * NROW + t + 1024 * k];
            vk[k] = 1.0f; uk[k] = AC; pv2[k] = 0xFFFFFFFFu;
        }
        unsigned flags = 3u;
        int par = 0, last = 0, done = 0;
        float bu_last = 0.f;
        for (int it = 0; it < NWARM; it++) {
            float s = 0.f;
            #pragma unroll
            for (int k = 0; k < 8; k++) s += vk[k];
            for (int o = 32; o; o >>= 1) s += __shfl_down(s, o, 64);
            if (lane == 0) { redS[par][wid] = s; redC[wid] = flags; }
            __syncthreads();
            float sumv = 0.f; unsigned anyf = 0;
            #pragma unroll
            for (int w2 = 0; w2 < 16; w2++) { sumv += redS[par][w2]; anyf |= redC[w2]; }
            par ^= 1;
            if (it > 0) {
                if (!(anyf & 1)) { done = 1; break; }
                if (!(anyf & 2)) {
                    if (((NITERS - it) & 1) == 0) { done = 1; break; }
                    last = 1;
                }
            }
            float base = 1e-8f * sumv;
            #pragma unroll
            for (int k = 0; k < 8; k++) {
                float kv = fmaxf(base + sk[k] * vk[k], 1e-8f);
                uk[k] = AC * __builtin_amdgcn_rcpf(kv);
            }
            s = 0.f;
            #pragma unroll
            for (int k = 0; k < 8; k++) s += uk[k];
            for (int o = 32; o; o >>= 1) s += __shfl_down(s, o, 64);
            if (lane == 0) redS[par][wid] = s;
            __syncthreads();
            float sumu = 0.f;
            #pragma unroll
            for (int w2 = 0; w2 < 16; w2++) sumu += redS[par][w2];
            par ^= 1;
            base = 1e-8f * sumu;
            bu_last = base;
            unsigned d1 = 0, d2 = 0;
            #pragma unroll
            for (int k = 0; k < 8; k++) {
                float kv = fmaxf(base + sk[k] * uk[k], 1e-8f);
                float nv = AC * __builtin_amdgcn_rcpf(kv);
                unsigned nb_ = __float_as_uint(nv);
                d1 |= nb_ ^ __float_as_uint(vk[k]);
                d2 |= nb_ ^ pv2[k];
                pv2[k] = __float_as_uint(vk[k]);
                vk[k] = nv;
            }
            flags = (__any(d1 != 0) ? 1u : 0u) | (__any(d2 != 0) ? 2u : 0u);
            if (last) { done = 1; break; }
        }
        float bv_f = 0.f;
        int R = 0;
        if (!done) {
            float s = 0.f;
            #pragma unroll
            for (int k = 0; k < 8; k++) s += vk[k];
            for (int o = 32; o; o >>= 1) s += __shfl_down(s, o, 64);
            if (lane == 0) redS[par][wid] = s;
            __syncthreads();
            float sumv = 0.f;
            #pragma unroll
            for (int w2 = 0; w2 < 16; w2++) sumv += redS[par][w2];
            bv_f = 1e-8f * sumv;
            R = NITERS - NWARM;
        }
        #pragma unroll
        for (int k = 0; k < 8; k++) {
            int i = t + 1024 * k;
            up[i] = uk[k]; vp[i] = vk[k];
        }
        if (t == 0) { acc[5] = (double)R; acc[6] = (double)bu_last; acc[7] = (double)bv_f; }
    } else {
        // fallback: general sparse scatter, full 100 iterations
        for (int i = t; i < NROW; i += 1024) { u_s[i] = 1.0f; v_s[i] = 1.0f; }
        __syncthreads();
        for (int it = 0; it < NITERS; it++) {
            {
                float sv = 0.f;
                for (int i = t; i < NROW; i += 1024) sv += v_s[i];
                for (int o = 32; o; o >>= 1) sv += __shfl_down(sv, o, 64);
                if (lane == 0) u_s[wid] = sv;
                __syncthreads();
                if (t < 64) {
                    float s2 = (t < 16) ? u_s[t] : 0.f;
                    for (int o = 8; o; o >>= 1) s2 += __shfl_down(s2, o, 64);
                    if (t == 0) u_s[0] = s2;
                }
                __syncthreads();
                float sum_v = u_s[0];
                __syncthreads();
                for (int i = t; i < NROW; i += 1024) u_s[i] = 1e-8f * sum_v;
                __syncthreads();
                for (int e = t; e < cnt; e += 1024)
                    atomicAdd(&u_s[list[e].i], list[e].s * v_s[list[e].j]);
                __syncthreads();
                for (int i = t; i < NROW; i += 1024) u_s[i] = AC / fmaxf(u_s[i], 1e-8f);
                __syncthreads();
            }
            {
                float su = 0.f;
                for (int i = t; i < NROW; i += 1024) su += u_s[i];
                for (int o = 32; o; o >>= 1) su += __shfl_down(su, o, 64);
                if (lane == 0) v_s[wid] = su;
                __syncthreads();
                if (t < 64) {
                    float s2 = (t < 16) ? v_s[t] : 0.f;
                    for (int o = 8; o; o >>= 1) s2 += __shfl_down(s2, o, 64);
                    if (t == 0) v_s[0] = s2;
                }
                __syncthreads();
                float sum_u = v_s[0];
                __syncthreads();
                for (int i = t; i < NROW; i += 1024) v_s[i] = 1e-8f * sum_u;
                __syncthreads();
                for (int e = t; e < cnt; e += 1024)
                    atomicAdd(&v_s[list[e].j], list[e].s * u_s[list[e].i]);
                __syncthreads();
                for (int i = t; i < NROW; i += 1024) v_s[i] = AC / fmaxf(v_s[i], 1e-8f);
                __syncthreads();
            }
        }
        for (int i = t; i < NROW; i += 1024) { up[i] = u_s[i]; vp[i] = v_s[i]; }
        if (t == 0) { acc[5] = 0.0; acc[6] = 0.0; acc[7] = 0.0; }
    }
}

// Frozen-base per-lane iterations: no barriers, no cross-lane traffic.
__global__ __launch_bounds__(256) void sinkwide_k(const float* __restrict__ sdiag,
                                                  float* __restrict__ u_g,
                                                  float* __restrict__ v_g,
                                                  const double* __restrict__ accum) {
    int p = blockIdx.y;
    const double* acc = accum + (size_t)p * 264;
    int R = (int)acc[5];
    if (R <= 0) return;
    float bu = (float)acc[6], bv = (float)acc[7];
    int i = blockIdx.x * 256 + threadIdx.x;
    float s = sdiag[p * NROW + i];
    float v = v_g[p * NROW + i];
    float u = u_g[p * NROW + i];
    for (int r = 0; r < R; r++) {
        u = AC * __builtin_amdgcn_rcpf(fmaxf(bv + s * v, 1e-8f));
        v = AC * __builtin_amdgcn_rcpf(fmaxf(bu + s * u, 1e-8f));
    }
    u_g[p * NROW + i] = u;
    v_g[p * NROW + i] = v;
}

// off-diagonal sparse cost correction (diagonal handled in epi_k via tdiag)
__global__ void sp_k(const int* counts, const Entry* __restrict__ lists,
                     const float* __restrict__ u_g, const float* __restrict__ v_g,
                     double* accum) {
    int p = blockIdx.x;
    int cnt = counts[p]; if (cnt > CAP) cnt = CAP;
    const Entry* list = lists + (size_t)p * CAP;
    const float* up = u_g + (size_t)p * NROW;
    const float* vp = v_g + (size_t)p * NROW;
    __shared__ double red[4];
    int t = threadIdx.x, lane = t & 63, wid = t >> 6;
    double sp = 0.0;
    for (int e = t; e < cnt; e += 256) {
        Entry en = list[e];
        if (en.i != en.j && en.t != 0.f)
            sp += (double)up[en.i] * (double)vp[en.j] * (double)en.t;
    }
    for (int o = 32; o; o >>= 1) sp += __shfl_down(sp, o, 64);
    if (lane == 0) red[wid] = sp;
    __syncthreads();
    if (t == 0) {
        double tot = red[0] + red[1] + red[2] + red[3];
        atomicAdd(&accum[(size_t)p * 264 + 4], tot);
    }
}

// wide-grid epilogue: Su, Sv, Sux2, Svy2, diag-sp, P[d], Q[d]
__global__ __launch_bounds__(256) void epi_k(const float* __restrict__ X,
                                             const float* __restrict__ Y,
                                             const float* __restrict__ x2,
                                             const float* __restrict__ y2,
                                             const float* __restrict__ u_g,
                                             const float* __restrict__ v_g,
                                             const float* __restrict__ tdiag,
                                             double* accum) {
    int p = blockIdx.y;
    const float* A = (p == 2) ? Y : X;
    const float* B = (p == 0) ? Y : ((p == 1) ? X : Y);
    const float* na = (p == 2) ? y2 : x2;
    const float* nb = (p == 0) ? y2 : ((p == 1) ? x2 : y2);
    const float* up = u_g + (size_t)p * NROW;
    const float* vp = v_g + (size_t)p * NROW;
    double* acc = accum + (size_t)p * 264;
    int t = threadIdx.x, lane = t & 63;
    int rbase = blockIdx.x * 256;
    {
        int r = rbase + t;
        double ui = up[r], vi = vp[r];
        double a0 = ui, a1 = vi, a2 = ui * (double)na[r], a3 = vi * (double)nb[r];
        double a4 = ui * vi * (double)tdiag[p * NROW + r];
        for (int o = 32; o; o >>= 1) {
            a0 += __shfl_down(a0, o, 64); a1 += __shfl_down(a1, o, 64);
            a2 += __shfl_down(a2, o, 64); a3 += __shfl_down(a3, o, 64);
            a4 += __shfl_down(a4, o, 64);
        }
        if (lane == 0) {
            atomicAdd(&acc[0], a0); atomicAdd(&acc[1], a1);
            atomicAdd(&acc[2], a2); atomicAdd(&acc[3], a3);
            atomicAdd(&acc[4], a4);
        }
    }
    {
        int dq = (t & 31) * 4, g = t >> 5;
        double pp[4] = {0, 0, 0, 0}, qq[4] = {0, 0, 0, 0};
        for (int k = 0; k < 32; k++) {
            int r = rbase + g + 8 * k;
            float4 av = *(const float4*)(A + (size_t)r * DDIM + dq);
            float us = up[r];
            pp[0] += (double)us * av.x; pp[1] += (double)us * av.y;
            pp[2] += (double)us * av.z; pp[3] += (double)us * av.w;
            float4 bv = *(const float4*)(B + (size_t)r * DDIM + dq);
            float vs = vp[r];
            qq[0] += (double)vs * bv.x; qq[1] += (double)vs * bv.y;
            qq[2] += (double)vs * bv.z; qq[3] += (double)vs * bv.w;
        }
        #pragma unroll
        for (int m = 0; m < 4; m++) {
            atomicAdd(&acc[8 + dq + m], pp[m]);
            atomicAdd(&acc[136 + dq + m], qq[m]);
        }
    }
}

__global__ void combine_k(const double* __restrict__ accum, float* __restrict__ out) {
    int t = threadIdx.x;  // 64 threads
    __shared__ double costs[3];
    for (int p = 0; p < 3; p++) {
        const double* acc = accum + (size_t)p * 264;
        double part = acc[8 + t] * acc[136 + t] + acc[8 + 64 + t] * acc[136 + 64 + t];
        for (int o = 32; o; o >>= 1) part += __shfl_down(part, o, 64);
        if (t == 0) {
            double F = acc[2] * acc[1] + acc[0] * acc[3] - 2.0 * part;
            double c = 1e-8 * F + acc[4];
            costs[p] = (c > 0.0) ? c : 0.0;
        }
    }
    __syncthreads();
    if (t == 0) {
        double dv = costs[0] - 0.5 * (costs[1] + costs[2]);
        dv = fmin(fmax(dv, 0.0), 10000.0);
        out[0] = (float)dv;
    }
}

extern "C" void kernel_launch(void* const* d_in, const int* in_sizes, int n_in,
                              void* d_out, int out_size, void* d_ws, size_t ws_size,
                              hipStream_t stream) {
    const float* X = (const float*)d_in[0];
    const float* Y = (const float*)d_in[1];
    float* out = (float*)d_out;
    char* ws = (char*)d_ws;
    float* x2 = (float*)ws;
    float* y2 = (float*)(ws + 32768);
    int* counts = (int*)(ws + 65536);
    unsigned* minx = (unsigned*)(ws + 65568);
    unsigned* miny = (unsigned*)(ws + 65824);
    double* accum = (double*)(ws + 66080);
    Entry* lists = (Entry*)(ws + 72416);
    unsigned short* Xbf = (unsigned short*)(ws + 858848);    // overlay region
    float* sdiag = (float*)(ws + 858848);
    float* tdiag = (float*)(ws + 957152);
    float* u_g = (float*)(ws + 1055456);
    float* v_g = (float*)(ws + 1153760);
    unsigned short* Ybf = (unsigned short*)(ws + 2956000);

    init_k<<<(3 * NROW + 255) / 256, 256, 0, stream>>>(counts, minx, miny, accum, lists);
    norms_k<<<(2 * NROW) / 4, 256, 0, stream>>>(X, Y, x2, y2, minx, miny, Xbf, Ybf);
    scan3_k<<<dim3(64, 64, 3), 256, 0, stream>>>(Xbf, Ybf, x2, y2, minx, miny, counts, lists);
    exact_k<<<dim3(2048, 3), 256, 0, stream>>>(X, Y, x2, y2, counts, lists);
    compact_k<<<dim3(CAP / 256, 3), 256, 0, stream>>>(counts, lists, sdiag, tdiag, counts + 3);
    sink2_k<<<3, 1024, 0, stream>>>(counts, lists, sdiag, u_g, v_g, accum);
    sinkwide_k<<<dim3(NROW / 256, 3), 256, 0, stream>>>(sdiag, u_g, v_g, accum);
    sp_k<<<3, 256, 0, stream>>>(counts, lists, u_g, v_g, accum);
    epi_k<<<dim3(NROW / 256, 3), 256, 0, stream>>>(X, Y, x2, y2, u_g, v_g, tdiag, accum);
    combine_k<<<1, 64, 0, stream>>>(accum, out);
}